// Round 3
// baseline (176.461 us; speedup 1.0000x reference)
//
#include <hip/hip_runtime.h>
#include <cstdint>
#include <cstddef>

#define N_NODES 50000
#define N_EDGES 640000
#define DF 128

#define NBUCK 196          // buckets of 256 nodes: bucket = dst >> 8
#define BCAP  6144         // staging capacity per bucket (mean 3265, +50 sigma)
#define PA_BLOCKS 250      // PassA blocks, 2560 edges each (250*2560 = 640000)
#define GEMM_BLOCKS 782    // ceil(3125 waves / 4), 4 waves per 256-thr block
#define FRAG_BLOCKS 16     // Wn1/Wn2 fragment conversion (2 * 2048 threads)

typedef __attribute__((ext_vector_type(8))) short bf16x8;
typedef __attribute__((ext_vector_type(4))) float f32x4;

__device__ inline unsigned short f2bf(float f) {            // RNE float->bf16
    unsigned int u = __float_as_uint(f);
    return (unsigned short)((u + 0x7fffu + ((u >> 16) & 1u)) >> 16);
}

// ================= K1: PassA || gemm_pool(from fp32 feat) || Wn frags ========
// R2 post-mortem: K1+K2 ≈ 74 µs combined; gemm_pool in K2 had a FALSE
// dependency on K1's featb — hb = feat@Wp^T computed directly from fp32
// feat (A converted in-register, featb written as by-product; dedicated
// featb-conversion blocks deleted). Each GEMM block converts W_pool (64 KB,
// L2-hot) into a 32 KB LDS fragment buffer once, then MFMAs with B from LDS.
// K2 becomes PassB-only (exposes its true cost in counters).
// blocks [0,250):        PassA — bin 2560 edges into 196 coarse buckets.
// blocks [250,1032):     gemm_pool: hb = bf16(feat @ Wp^T + b_pool), +featb
// blocks [1032,1048):    Wn1/Wn2 fragments (B-operand order for 16x16x32)
__global__ __launch_bounds__(256) void k1_setup_bucket(
    const float* __restrict__ feat,
    const float* __restrict__ W_pool,
    const float* __restrict__ W_neigh,
    const float* __restrict__ b_pool,
    const int* __restrict__ src,
    const int* __restrict__ dst,
    const float* __restrict__ w,
    unsigned short* __restrict__ featb,
    unsigned short* __restrict__ hb,
    unsigned short* __restrict__ Wn1_f,
    unsigned short* __restrict__ Wn2_f,
    int* __restrict__ bucketcnt,        // pre-zeroed via hipMemsetAsync
    uint2* __restrict__ staging)
{
    int bid = blockIdx.x;
    int t = threadIdx.x;
    if (bid < PA_BLOCKS) {
        __shared__ int cnt[NBUCK];
        __shared__ int runbase[NBUCK];
        int base = bid * 2560;
        if (t < NBUCK) cnt[t] = 0;
        __syncthreads();
        uint2 rec[10];
        int bk[10];
        #pragma unroll
        for (int i = 0; i < 10; ++i) {
            int e = base + i * 256 + t;
            int s = src[e], d = dst[e];
            bk[i] = d >> 8;
            rec[i].x = (unsigned int)s | ((unsigned int)(d & 255) << 16);
            rec[i].y = __float_as_uint(w[e]);
            atomicAdd(&cnt[bk[i]], 1);
        }
        __syncthreads();
        if (t < NBUCK) {
            runbase[t] = atomicAdd(&bucketcnt[t], cnt[t]);
            cnt[t] = 0;                 // reuse as within-run cursor
        }
        __syncthreads();
        #pragma unroll
        for (int i = 0; i < 10; ++i) {
            int r = atomicAdd(&cnt[bk[i]], 1);
            int pos = runbase[bk[i]] + r;
            if (pos < BCAP) staging[bk[i] * BCAP + pos] = rec[i];
        }
    } else if (bid < PA_BLOCKS + GEMM_BLOCKS) {
        // ---- gemm_pool from fp32 feat, B-fragments staged once in LDS ----
        __shared__ __align__(16) unsigned short wsh[16384];   // 32 KB Wp frags
        #pragma unroll
        for (int k = 0; k < 8; ++k) {
            int r8 = t * 8 + k;               // 0..2047 fragment id
            int L = r8 & 63, tt2 = (r8 >> 6) & 3, c = r8 >> 8;
            const float* srcp = W_pool + (c * 16 + (L & 15)) * 128
                                       + tt2 * 32 + (L >> 4) * 8;
            float4 a = ((const float4*)srcp)[0];
            float4 b = ((const float4*)srcp)[1];
            ushort4 lo, hi;
            lo.x = f2bf(a.x); lo.y = f2bf(a.y); lo.z = f2bf(a.z); lo.w = f2bf(a.w);
            hi.x = f2bf(b.x); hi.y = f2bf(b.y); hi.z = f2bf(b.z); hi.w = f2bf(b.w);
            ((ushort4*)(wsh + r8 * 8))[0] = lo;
            ((ushort4*)(wsh + r8 * 8))[1] = hi;
        }
        __syncthreads();

        int gwave = (bid - PA_BLOCKS) * 4 + (t >> 6);
        int m0 = gwave * 16;
        if (m0 < N_NODES) {
            int lane = t & 63;
            const int n = lane & 15, quad = lane >> 4;
            f32x4 acc[8];
            #pragma unroll
            for (int c = 0; c < 8; ++c) {
                float bv = b_pool[c * 16 + n];
                acc[c] = (f32x4){bv, bv, bv, bv};
            }
            const float* fp = feat + (size_t)(m0 + n) * DF + quad * 8;
            unsigned short* fbp = featb + (size_t)(m0 + n) * DF + quad * 8;
            #pragma unroll
            for (int tt = 0; tt < 4; ++tt) {
                float4 a = ((const float4*)(fp + tt * 32))[0];
                float4 b = ((const float4*)(fp + tt * 32))[1];
                union { bf16x8 v; ushort4 u4[2]; } af;
                af.u4[0].x = f2bf(a.x); af.u4[0].y = f2bf(a.y);
                af.u4[0].z = f2bf(a.z); af.u4[0].w = f2bf(a.w);
                af.u4[1].x = f2bf(b.x); af.u4[1].y = f2bf(b.y);
                af.u4[1].z = f2bf(b.z); af.u4[1].w = f2bf(b.w);
                *(bf16x8*)(fbp + tt * 32) = af.v;          // featb by-product
                #pragma unroll
                for (int c = 0; c < 8; ++c) {
                    bf16x8 bfv = *(const bf16x8*)(wsh + (size_t)((c * 4 + tt) * 64 + lane) * 8);
                    acc[c] = __builtin_amdgcn_mfma_f32_16x16x32_bf16(af.v, bfv, acc[c], 0, 0, 0);
                }
            }
            #pragma unroll
            for (int c = 0; c < 8; ++c)
                #pragma unroll
                for (int r = 0; r < 4; ++r)
                    hb[(size_t)(m0 + quad * 4 + r) * DF + c * 16 + n] = f2bf(acc[c][r]);
        }
    } else {
        int g = (bid - PA_BLOCKS - GEMM_BLOCKS) * 256 + t;   // < 4096
        int m = g >> 11;                 // 0: Wn1, 1: Wn2
        int r8 = g & 2047;               // (c*tt)*64 + L fragment id
        int L = r8 & 63, tt = (r8 >> 6) & 3, c = r8 >> 8;
        int o = c * 16 + (L & 15);
        int kb = tt * 32 + (L >> 4) * 8;
        const float* srcp = W_neigh + o * 256 + (m ? 128 : 0) + kb;
        unsigned short* dstp = m ? Wn2_f : Wn1_f;
        ushort4 lo, hi;
        float4 a = ((const float4*)srcp)[0];
        float4 b = ((const float4*)srcp)[1];
        lo.x = f2bf(a.x); lo.y = f2bf(a.y); lo.z = f2bf(a.z); lo.w = f2bf(a.w);
        hi.x = f2bf(b.x); hi.y = f2bf(b.y); hi.z = f2bf(b.z); hi.w = f2bf(b.w);
        ((ushort4*)(dstp + r8 * 8))[0] = lo;
        ((ushort4*)(dstp + r8 * 8))[1] = hi;
    }
}

// ================= K2: PassB only (per-bucket fine sort) =====================
// bucket b: base = prefix(bucketcnt), count+scan per-node degrees in LDS,
// write offsets, re-scatter records into final dst-sorted edges[].
__global__ __launch_bounds__(1024) void k2_passb(
    const int* __restrict__ bucketcnt,
    const uint2* __restrict__ staging,
    int* __restrict__ offsets,
    uint2* __restrict__ edges)
{
    int t = threadIdx.x;
    __shared__ int dcnt[256];       // per-node count, then global cursor
    __shared__ int sc[256];         // scan scratch
    __shared__ int bc[256];         // bucket counts
    int b = blockIdx.x;             // 0..195

    if (t < 256) { dcnt[t] = 0; bc[t] = (t < NBUCK) ? bucketcnt[t] : 0; sc[t] = (t < NBUCK) ? bc[t] : 0; }
    __syncthreads();
    // exclusive prefix of bucket counts (Hillis-Steele over 256)
    #pragma unroll
    for (int off = 1; off < 256; off <<= 1) {
        int u = (t < 256 && t >= off) ? sc[t - off] : 0;
        __syncthreads();
        if (t < 256) sc[t] += u;
        __syncthreads();
    }
    int mybase = (b > 0) ? sc[b - 1] : 0;
    int cnt = bc[b];
    __syncthreads();                 // sc about to be reused

    // load my staged records, count per-node degrees
    uint2 rec[6];
    int nit = (cnt + 1023) >> 10;
    for (int i = 0; i < nit; ++i) {
        int idx = i * 1024 + t;
        if (idx < cnt) {
            rec[i] = staging[(size_t)b * BCAP + idx];
            atomicAdd(&dcnt[(rec[i].x >> 16) & 255], 1);
        }
    }
    __syncthreads();
    if (t < 256) sc[t] = dcnt[t];
    __syncthreads();
    #pragma unroll
    for (int off = 1; off < 256; off <<= 1) {
        int u = (t < 256 && t >= off) ? sc[t - off] : 0;
        __syncthreads();
        if (t < 256) sc[t] += u;
        __syncthreads();
    }
    if (t < 256) {
        int node = b * 256 + t;
        int excl = sc[t] - dcnt[t];
        if (node < N_NODES) offsets[node] = mybase + excl;
        dcnt[t] = mybase + excl;     // repurpose: global write cursor
    }
    if (b == NBUCK - 1 && t == 0) offsets[N_NODES] = mybase + cnt;
    __syncthreads();
    for (int i = 0; i < nit; ++i) {
        int idx = i * 1024 + t;
        if (idx < cnt) {
            int dl = (rec[i].x >> 16) & 255;
            int pos = atomicAdd(&dcnt[dl], 1);
            uint2 fin;
            fin.x = rec[i].x & 0xFFFFu;     // src
            fin.y = rec[i].y;               // w bits
            edges[pos] = fin;
        }
    }
}

// ========== K3fused v2: per-node max + output GEMM, 1 node per WAVE =========
// block = 1024 thr = 16 waves = 16 nodes, ONE node per wave (50,000 waves —
// verified R2: 44.7 µs, Occ 63%). Grid 3125 blocks (exact).
//   gather (all 16 waves): old K3 loop verbatim, row -> swizzled LDS tile.
//   waves 0-7 then compute ONE 16-col block each of the output tile:
//     featb@Wn1 half issued BEFORE the barrier (global operands only —
//     absorbs intra-block gather imbalance), nsh@Wn2 half after.
//   waves 8-15 exit at the barrier and free their slots.
__global__ __launch_bounds__(1024) void fused_max_out(
    const unsigned short* __restrict__ featb,
    const unsigned short* __restrict__ hb,
    const int* __restrict__ offsets,
    const uint2* __restrict__ edges,
    const unsigned short* __restrict__ Wn1_f,
    const unsigned short* __restrict__ Wn2_f,
    const float* __restrict__ bias,
    float* __restrict__ out)
{
    __shared__ __align__(16) unsigned short nsh[16 * DF];   // swizzled 16x128 bf16
    const int t = threadIdx.x;
    const int lane = t & 63;
    const int wid = t >> 6;          // 0..15 == row within tile
    const int m0 = blockIdx.x * 16;
    const int half = lane >> 5;      // 0: even edge of pair, 1: odd edge
    const int q = lane & 31;         // column quarter: cols 4q..4q+3

    const int node = __builtin_amdgcn_readfirstlane(m0 + wid);
    int beg = offsets[node], end = offsets[node + 1];
    float4 mx = make_float4(-3.4e38f, -3.4e38f, -3.4e38f, -3.4e38f);

    for (int e = beg; e < end; e += 8) {
        int i1 = min(e + 1, end - 1);
        int i2 = min(e + 2, end - 1);
        int i3 = min(e + 3, end - 1);
        int i4 = min(e + 4, end - 1);
        int i5 = min(e + 5, end - 1);
        int i6 = min(e + 6, end - 1);
        int i7 = min(e + 7, end - 1);
        uint2 e0 = edges[e],  e1 = edges[i1], e2 = edges[i2], e3 = edges[i3];
        uint2 e4 = edges[i4], e5 = edges[i5], e6 = edges[i6], e7 = edges[i7];
        uint2 mA = half ? e1 : e0;
        uint2 mB = half ? e3 : e2;
        uint2 mC = half ? e5 : e4;
        uint2 mD = half ? e7 : e6;
        float wA = __uint_as_float(mA.y);
        float wB = __uint_as_float(mB.y);
        float wC = __uint_as_float(mC.y);
        float wD = __uint_as_float(mD.y);
        uint2 pA = *(const uint2*)(hb + (size_t)mA.x * DF + q * 4);
        uint2 pB = *(const uint2*)(hb + (size_t)mB.x * DF + q * 4);
        uint2 pC = *(const uint2*)(hb + (size_t)mC.x * DF + q * 4);
        uint2 pD = *(const uint2*)(hb + (size_t)mD.x * DF + q * 4);
        mx.x = fmaxf(mx.x, __uint_as_float(pA.x << 16)          * wA);
        mx.y = fmaxf(mx.y, __uint_as_float(pA.x & 0xffff0000u)  * wA);
        mx.z = fmaxf(mx.z, __uint_as_float(pA.y << 16)          * wA);
        mx.w = fmaxf(mx.w, __uint_as_float(pA.y & 0xffff0000u)  * wA);
        mx.x = fmaxf(mx.x, __uint_as_float(pB.x << 16)          * wB);
        mx.y = fmaxf(mx.y, __uint_as_float(pB.x & 0xffff0000u)  * wB);
        mx.z = fmaxf(mx.z, __uint_as_float(pB.y << 16)          * wB);
        mx.w = fmaxf(mx.w, __uint_as_float(pB.y & 0xffff0000u)  * wB);
        mx.x = fmaxf(mx.x, __uint_as_float(pC.x << 16)          * wC);
        mx.y = fmaxf(mx.y, __uint_as_float(pC.x & 0xffff0000u)  * wC);
        mx.z = fmaxf(mx.z, __uint_as_float(pC.y << 16)          * wC);
        mx.w = fmaxf(mx.w, __uint_as_float(pC.y & 0xffff0000u)  * wC);
        mx.x = fmaxf(mx.x, __uint_as_float(pD.x << 16)          * wD);
        mx.y = fmaxf(mx.y, __uint_as_float(pD.x & 0xffff0000u)  * wD);
        mx.z = fmaxf(mx.z, __uint_as_float(pD.y << 16)          * wD);
        mx.w = fmaxf(mx.w, __uint_as_float(pD.y & 0xffff0000u)  * wD);
    }

    float4 o;
    o.x = fmaxf(mx.x, __shfl_xor(mx.x, 32));
    o.y = fmaxf(mx.y, __shfl_xor(mx.y, 32));
    o.z = fmaxf(mx.z, __shfl_xor(mx.z, 32));
    o.w = fmaxf(mx.w, __shfl_xor(mx.w, 32));
    if (beg == end) o = make_float4(0.f, 0.f, 0.f, 0.f);
    if (half == 0) {
        ushort4 ob;
        ob.x = f2bf(o.x); ob.y = f2bf(o.y); ob.z = f2bf(o.z); ob.w = f2bf(o.w);
        int boff = wid * 256 + ((q * 8) ^ ((wid & 7) << 4));   // 8B-aligned
        *(ushort4*)((char*)nsh + boff) = ob;
    }

    // -------- phase 2: waves 0-7 each compute one 16-col block --------------
    const int n = lane & 15, quad = lane >> 4;
    f32x4 acc;
    if (wid < 8) {
        const int c = wid;
        float bv = bias[c * 16 + n];
        acc = (f32x4){bv, bv, bv, bv};
        const unsigned short* a0 = featb + (size_t)(m0 + n) * DF + quad * 8;
        #pragma unroll
        for (int tt = 0; tt < 4; ++tt) {
            bf16x8 af = *(const bf16x8*)(a0 + tt * 32);
            bf16x8 bfv = *(const bf16x8*)(Wn1_f + (size_t)((c * 4 + tt) * 64 + lane) * 8);
            acc = __builtin_amdgcn_mfma_f32_16x16x32_bf16(af, bfv, acc, 0, 0, 0);
        }
    }

    __syncthreads();                     // nsh fully written by all waves
    if (wid >= 8) return;                // free slots; waves 0-7 finish tile

    const int c = wid;
    #pragma unroll
    for (int tt = 0; tt < 4; ++tt) {
        int boff = (quad * 16 + tt * 64) ^ ((n & 7) << 4);         // 16B-aligned
        bf16x8 af = *(const bf16x8*)((const char*)nsh + n * 256 + boff);
        bf16x8 bfv = *(const bf16x8*)(Wn2_f + (size_t)((c * 4 + tt) * 64 + lane) * 8);
        acc = __builtin_amdgcn_mfma_f32_16x16x32_bf16(af, bfv, acc, 0, 0, 0);
    }

    #pragma unroll
    for (int r = 0; r < 4; ++r)
        out[(size_t)(m0 + quad * 4 + r) * DF + c * 16 + n] = acc[r];
}

extern "C" void kernel_launch(void* const* d_in, const int* in_sizes, int n_in,
                              void* d_out, int out_size, void* d_ws, size_t ws_size,
                              hipStream_t stream) {
    const float* feat    = (const float*)d_in[0];
    const float* weight  = (const float*)d_in[1];
    const int*   src     = (const int*)d_in[2];
    const int*   dst     = (const int*)d_in[3];
    const float* W_pool  = (const float*)d_in[4];
    const float* b_pool  = (const float*)d_in[5];
    const float* W_neigh = (const float*)d_in[6];
    const float* b_neigh = (const float*)d_in[7];
    float* out = (float*)d_out;

    char* ws = (char*)d_ws;
    unsigned short* featb  = (unsigned short*)(ws);              // 12,800,000 B
    unsigned short* hb     = (unsigned short*)(ws + 12800000);   // 12,800,000 B
    // (ws + 25600000 .. 38400000 unused)
    unsigned short* Wn1_f  = (unsigned short*)(ws + 38432768);   // 32,768 B
    unsigned short* Wn2_f  = (unsigned short*)(ws + 38465536);   // 32,768 B
    int*   offsets   = (int*)  (ws + 38498304);                  // 200,064 B
    int*   bucketcnt = (int*)  (ws + 38698368);                  // 1,024 B
    uint2* staging   = (uint2*)(ws + 38699392);                  // 9,633,792 B
    uint2* edges     = (uint2*)(ws + 48333184);                  // 5,120,000 B -> ~53.5 MB

    hipMemsetAsync(bucketcnt, 0, 1024, stream);

    // K1: PassA || gemm_pool (feat fp32 -> hb + featb) || Wn fragments
    const int K1_BLOCKS = PA_BLOCKS + GEMM_BLOCKS + FRAG_BLOCKS;   // 1048
    k1_setup_bucket<<<K1_BLOCKS, 256, 0, stream>>>(
        feat, W_pool, W_neigh, b_pool, src, dst, weight,
        featb, hb, Wn1_f, Wn2_f, bucketcnt, staging);

    // K2: PassB (offsets + final dst-sorted edges)
    k2_passb<<<NBUCK, 1024, 0, stream>>>(
        bucketcnt, staging, offsets, edges);

    // K3fused: segment-max gather (1 node/wave) + out GEMM
    fused_max_out<<<N_NODES / 16, 1024, 0, stream>>>(
        featb, hb, offsets, edges, Wn1_f, Wn2_f, b_neigh, out);
}

// Round 4
// 162.327 us; speedup vs baseline: 1.0871x; 1.0871x over previous
//
#include <hip/hip_runtime.h>
#include <cstdint>
#include <cstddef>

#define N_NODES 50000
#define N_EDGES 640000
#define DF 128

#define NBUCK 196          // buckets of 256 nodes: bucket = dst >> 8
#define BCAP  6144         // staging capacity per bucket (mean 3265, +50 sigma)
#define ECAP  8192         // final per-bucket edge region (6144 + 256*7 pad max = 7936)
#define PA_BLOCKS 250      // PassA blocks, 2560 edges each (250*2560 = 640000)
#define DUMMY_ROW 50000    // hb row filled with -3.39e38 (pad records point here)

typedef __attribute__((ext_vector_type(8))) short bf16x8;
typedef __attribute__((ext_vector_type(4))) float f32x4;

__device__ inline unsigned short f2bf(float f) {            // RNE float->bf16
    unsigned int u = __float_as_uint(f);
    return (unsigned short)((u + 0x7fffu + ((u >> 16) & 1u)) >> 16);
}

// ================= K1: PassA (coarse bucket sort) || setup ===================
// R3 post-mortem: moving gemm_pool here regressed (K2=PassB-alone had nothing
// to overlap). Reverted to the R2-validated split.
// blocks [0,250):        PassA — bin 2560 edges into 196 coarse buckets.
// blocks [250,6500):     featb = bf16(feat)
// blocks [6500,6524):    W fragments (B-operand order for 16x16x32 MFMA)
// block  6524:           hb[DUMMY_ROW] = bf16(-3.39e38) for pad records
#define NF4 (N_NODES * DF / 4)        // 1,600,000
#define NWG (3 * 2048)
__global__ __launch_bounds__(256) void k1_setup_bucket(
    const float* __restrict__ feat,
    const float* __restrict__ W_pool,
    const float* __restrict__ W_neigh,
    const int* __restrict__ src,
    const int* __restrict__ dst,
    const float* __restrict__ w,
    unsigned short* __restrict__ featb,
    unsigned short* __restrict__ hb,
    unsigned short* __restrict__ Wp_f,
    unsigned short* __restrict__ Wn1_f,
    unsigned short* __restrict__ Wn2_f,
    int* __restrict__ bucketcnt,        // pre-zeroed via hipMemsetAsync
    uint2* __restrict__ staging)
{
    int bid = blockIdx.x;
    int t = threadIdx.x;
    if (bid < PA_BLOCKS) {
        __shared__ int cnt[NBUCK];
        __shared__ int runbase[NBUCK];
        int base = bid * 2560;
        if (t < NBUCK) cnt[t] = 0;
        __syncthreads();
        uint2 rec[10];
        int bk[10];
        #pragma unroll
        for (int i = 0; i < 10; ++i) {
            int e = base + i * 256 + t;
            int s = src[e], d = dst[e];
            bk[i] = d >> 8;
            rec[i].x = (unsigned int)s | ((unsigned int)(d & 255) << 16);
            rec[i].y = __float_as_uint(w[e]);
            atomicAdd(&cnt[bk[i]], 1);
        }
        __syncthreads();
        if (t < NBUCK) {
            runbase[t] = atomicAdd(&bucketcnt[t], cnt[t]);
            cnt[t] = 0;                 // reuse as within-run cursor
        }
        __syncthreads();
        #pragma unroll
        for (int i = 0; i < 10; ++i) {
            int r = atomicAdd(&cnt[bk[i]], 1);
            int pos = runbase[bk[i]] + r;
            if (pos < BCAP) staging[bk[i] * BCAP + pos] = rec[i];
        }
    } else if (bid < 250 + NF4 / 256) {
        int idx = (bid - PA_BLOCKS) * 256 + t;
        float4 v = ((const float4*)feat)[idx];
        ushort4 o;
        o.x = f2bf(v.x); o.y = f2bf(v.y); o.z = f2bf(v.z); o.w = f2bf(v.w);
        ((ushort4*)featb)[idx] = o;
    } else if (bid < 250 + NF4 / 256 + NWG / 256) {
        int g = (bid - PA_BLOCKS - NF4 / 256) * 256 + t;   // < NWG
        int m = g >> 11;
        int r8 = g & 2047;          // (c*4+tt)*64 + L
        int L = r8 & 63, tt = (r8 >> 6) & 3, c = r8 >> 8;
        int o = c * 16 + (L & 15);
        int kb = tt * 32 + (L >> 4) * 8;
        const float* srcp;
        unsigned short* dstp;
        if (m == 0)      { srcp = W_pool  + o * 128 + kb;       dstp = Wp_f;  }
        else if (m == 1) { srcp = W_neigh + o * 256 + kb;       dstp = Wn1_f; }
        else             { srcp = W_neigh + o * 256 + 128 + kb; dstp = Wn2_f; }
        ushort4 lo, hi;
        float4 a = ((const float4*)srcp)[0];
        float4 b = ((const float4*)srcp)[1];
        lo.x = f2bf(a.x); lo.y = f2bf(a.y); lo.z = f2bf(a.z); lo.w = f2bf(a.w);
        hi.x = f2bf(b.x); hi.y = f2bf(b.y); hi.z = f2bf(b.z); hi.w = f2bf(b.w);
        ((ushort4*)(dstp + r8 * 8))[0] = lo;
        ((ushort4*)(dstp + r8 * 8))[1] = hi;
    } else {
        // dummy hb row: bf16 -3.39e38 — pad-record messages never win the max
        if (t < DF) hb[(size_t)DUMMY_ROW * DF + t] = 0xFF7Fu;
    }
}

// ================= K2: gemm_pool || PassB (per-bucket fine sort) =============
// blocks [0,196):  gemm_pool — hb = bf16(featb @ Wp^T + b_pool), 16 waves/blk
// blocks [196,392): PassB — bucket b owns edges[b*ECAP .. ): count per-node
//   degrees in LDS, scan PADDED (round-up-8) counts, write offsets/nend,
//   fill pad slots with dummy records, re-scatter real records dst-sorted.
//   Fixed per-bucket regions: NO cross-bucket prefix scan needed (deleted).
#define GEMMB 196          // ceil(3125 waves / 16)
__global__ __launch_bounds__(1024) void k2_gemm_passb(
    const unsigned short* __restrict__ featb,
    const unsigned short* __restrict__ Wp_f,
    const float* __restrict__ b_pool,
    unsigned short* __restrict__ hb,
    const int* __restrict__ bucketcnt,
    const uint2* __restrict__ staging,
    int* __restrict__ offsets,
    int* __restrict__ nend,
    uint2* __restrict__ edges)
{
    int t = threadIdx.x;
    if (blockIdx.x < GEMMB) {
        int wave = blockIdx.x * 16 + (t >> 6);
        int lane = t & 63;
        int m0 = wave * 16;
        if (m0 >= N_NODES) return;          // no barriers on this path
        const int n = lane & 15, quad = lane >> 4;

        f32x4 acc[8];
        #pragma unroll
        for (int c = 0; c < 8; ++c) {
            float bv = b_pool[c * 16 + n];
            acc[c] = (f32x4){bv, bv, bv, bv};
        }
        const unsigned short* aptr = featb + (size_t)(m0 + n) * DF + quad * 8;
        #pragma unroll
        for (int tt = 0; tt < 4; ++tt) {
            bf16x8 af = *(const bf16x8*)(aptr + tt * 32);
            #pragma unroll
            for (int c = 0; c < 8; ++c) {
                bf16x8 bf = *(const bf16x8*)(Wp_f + (size_t)((c * 4 + tt) * 64 + lane) * 8);
                acc[c] = __builtin_amdgcn_mfma_f32_16x16x32_bf16(af, bf, acc[c], 0, 0, 0);
            }
        }
        #pragma unroll
        for (int c = 0; c < 8; ++c)
            #pragma unroll
            for (int r = 0; r < 4; ++r)
                hb[(size_t)(m0 + quad * 4 + r) * DF + c * 16 + n] = f2bf(acc[c][r]);
    } else {
        __shared__ int dcnt[256];       // per-node count, then global cursor
        __shared__ int sc[256];         // scan scratch (padded counts)
        int b = blockIdx.x - GEMMB;     // 0..195
        int cnt = bucketcnt[b];
        if (cnt > BCAP) cnt = BCAP;     // PassA dropped overflow records

        if (t < 256) dcnt[t] = 0;
        __syncthreads();

        // load my staged records, count per-node degrees
        uint2 rec[6];
        int nit = (cnt + 1023) >> 10;
        for (int i = 0; i < nit; ++i) {
            int idx = i * 1024 + t;
            if (idx < cnt) {
                rec[i] = staging[(size_t)b * BCAP + idx];
                atomicAdd(&dcnt[(rec[i].x >> 16) & 255], 1);
            }
        }
        __syncthreads();
        int mydeg = 0, mypad = 0;
        if (t < 256) {
            mydeg = dcnt[t];
            mypad = (mydeg + 7) & ~7;   // round segment up to multiple of 8
            sc[t] = mypad;
        }
        __syncthreads();
        #pragma unroll
        for (int off = 1; off < 256; off <<= 1) {
            int u = (t < 256 && t >= off) ? sc[t - off] : 0;
            __syncthreads();
            if (t < 256) sc[t] += u;
            __syncthreads();
        }
        if (t < 256) {
            int beg = b * ECAP + sc[t] - mypad;     // exclusive padded prefix
            int node = b * 256 + t;
            if (node < N_NODES) {
                offsets[node] = beg;
                nend[node] = beg + mypad;           // PADDED end — K3 loop bound
            }
            dcnt[t] = beg;                          // repurpose: write cursor
            uint2 dmy; dmy.x = DUMMY_ROW; dmy.y = 0x3F800000u;   // w = 1.0
            for (int k = mydeg; k < mypad; ++k) edges[beg + k] = dmy;
        }
        __syncthreads();
        for (int i = 0; i < nit; ++i) {
            int idx = i * 1024 + t;
            if (idx < cnt) {
                int dl = (rec[i].x >> 16) & 255;
                int pos = atomicAdd(&dcnt[dl], 1);
                uint2 fin;
                fin.x = rec[i].x & 0xFFFFu;     // src
                fin.y = rec[i].y;               // w bits
                edges[pos] = fin;
            }
        }
    }
}

// ================= K3: per-node max over incoming messages (1 wave/node) ====
// Un-fused again (R3 lesson: fusion's block barrier costs ~max-of-16-degrees
// per tile ≈ 1.9x gather inflation > the 25.6 MB neighb round-trip it saves).
// Segments are padded to 8 with dummy records (hb row DUMMY_ROW = -3.39e38,
// w=1) -> NO min-clamps, no end bookkeeping in the inner loop.
// R9 note still applies: 8-edge / low-VGPR form; gather is L3-BW-bound.
__global__ __launch_bounds__(256) void neigh_max_kernel(
    const unsigned short* __restrict__ hb, const int* __restrict__ offsets,
    const int* __restrict__ nend,
    const uint2* __restrict__ edges,
    unsigned short* __restrict__ neighb)
{
    int gwave = (blockIdx.x * 256 + threadIdx.x) >> 6;
    if (gwave >= N_NODES) return;
    int node = __builtin_amdgcn_readfirstlane(gwave);
    int lane = threadIdx.x & 63;
    const int half = lane >> 5;      // 0: even edge of pair, 1: odd edge
    const int q = lane & 31;         // column quarter: cols 4q..4q+3

    int beg = offsets[node], end = nend[node];   // end is padded (multiple of 8)
    float4 acc = make_float4(-3.4e38f, -3.4e38f, -3.4e38f, -3.4e38f);

    for (int e = beg; e < end; e += 8) {
        uint2 e0 = edges[e],     e1 = edges[e + 1], e2 = edges[e + 2], e3 = edges[e + 3];
        uint2 e4 = edges[e + 4], e5 = edges[e + 5], e6 = edges[e + 6], e7 = edges[e + 7];
        uint2 mA = half ? e1 : e0;
        uint2 mB = half ? e3 : e2;
        uint2 mC = half ? e5 : e4;
        uint2 mD = half ? e7 : e6;
        float wA = __uint_as_float(mA.y);
        float wB = __uint_as_float(mB.y);
        float wC = __uint_as_float(mC.y);
        float wD = __uint_as_float(mD.y);
        uint2 pA = *(const uint2*)(hb + (size_t)mA.x * DF + q * 4);
        uint2 pB = *(const uint2*)(hb + (size_t)mB.x * DF + q * 4);
        uint2 pC = *(const uint2*)(hb + (size_t)mC.x * DF + q * 4);
        uint2 pD = *(const uint2*)(hb + (size_t)mD.x * DF + q * 4);
        acc.x = fmaxf(acc.x, __uint_as_float(pA.x << 16)          * wA);
        acc.y = fmaxf(acc.y, __uint_as_float(pA.x & 0xffff0000u)  * wA);
        acc.z = fmaxf(acc.z, __uint_as_float(pA.y << 16)          * wA);
        acc.w = fmaxf(acc.w, __uint_as_float(pA.y & 0xffff0000u)  * wA);
        acc.x = fmaxf(acc.x, __uint_as_float(pB.x << 16)          * wB);
        acc.y = fmaxf(acc.y, __uint_as_float(pB.x & 0xffff0000u)  * wB);
        acc.z = fmaxf(acc.z, __uint_as_float(pB.y << 16)          * wB);
        acc.w = fmaxf(acc.w, __uint_as_float(pB.y & 0xffff0000u)  * wB);
        acc.x = fmaxf(acc.x, __uint_as_float(pC.x << 16)          * wC);
        acc.y = fmaxf(acc.y, __uint_as_float(pC.x & 0xffff0000u)  * wC);
        acc.z = fmaxf(acc.z, __uint_as_float(pC.y << 16)          * wC);
        acc.w = fmaxf(acc.w, __uint_as_float(pC.y & 0xffff0000u)  * wC);
        acc.x = fmaxf(acc.x, __uint_as_float(pD.x << 16)          * wD);
        acc.y = fmaxf(acc.y, __uint_as_float(pD.x & 0xffff0000u)  * wD);
        acc.z = fmaxf(acc.z, __uint_as_float(pD.y << 16)          * wD);
        acc.w = fmaxf(acc.w, __uint_as_float(pD.y & 0xffff0000u)  * wD);
    }

    float4 o;
    o.x = fmaxf(acc.x, __shfl_xor(acc.x, 32));
    o.y = fmaxf(acc.y, __shfl_xor(acc.y, 32));
    o.z = fmaxf(acc.z, __shfl_xor(acc.z, 32));
    o.w = fmaxf(acc.w, __shfl_xor(acc.w, 32));
    if (beg == end) o = make_float4(0.f, 0.f, 0.f, 0.f);
    if (half == 0) {
        ushort4 ob;
        ob.x = f2bf(o.x); ob.y = f2bf(o.y); ob.z = f2bf(o.z); ob.w = f2bf(o.w);
        *(ushort4*)(neighb + (size_t)node * DF + q * 4) = ob;
    }
}

// ================= K4: out = featb@Wn1^T + neighb@Wn2^T + b_neigh (fp32) ====
__global__ __launch_bounds__(256) void gemm_out(
    const unsigned short* __restrict__ featb,
    const unsigned short* __restrict__ neighb,
    const unsigned short* __restrict__ Wn1_f,
    const unsigned short* __restrict__ Wn2_f,
    const float* __restrict__ bias,
    float* __restrict__ out)
{
    int wave = (blockIdx.x * 256 + threadIdx.x) >> 6;
    int lane = threadIdx.x & 63;
    int m0 = wave * 16;
    if (m0 >= N_NODES) return;
    const int n = lane & 15, quad = lane >> 4;

    f32x4 acc[8];
    #pragma unroll
    for (int c = 0; c < 8; ++c) {
        float bv = bias[c * 16 + n];
        acc[c] = (f32x4){bv, bv, bv, bv};
    }

    const unsigned short* a0 = featb  + (size_t)(m0 + n) * DF + quad * 8;
    const unsigned short* a1 = neighb + (size_t)(m0 + n) * DF + quad * 8;
    #pragma unroll
    for (int t = 0; t < 4; ++t) {
        bf16x8 af = *(const bf16x8*)(a0 + t * 32);
        #pragma unroll
        for (int c = 0; c < 8; ++c) {
            bf16x8 bf = *(const bf16x8*)(Wn1_f + (size_t)((c * 4 + t) * 64 + lane) * 8);
            acc[c] = __builtin_amdgcn_mfma_f32_16x16x32_bf16(af, bf, acc[c], 0, 0, 0);
        }
    }
    #pragma unroll
    for (int t = 0; t < 4; ++t) {
        bf16x8 af = *(const bf16x8*)(a1 + t * 32);
        #pragma unroll
        for (int c = 0; c < 8; ++c) {
            bf16x8 bf = *(const bf16x8*)(Wn2_f + (size_t)((c * 4 + t) * 64 + lane) * 8);
            acc[c] = __builtin_amdgcn_mfma_f32_16x16x32_bf16(af, bf, acc[c], 0, 0, 0);
        }
    }

    #pragma unroll
    for (int c = 0; c < 8; ++c)
        #pragma unroll
        for (int r = 0; r < 4; ++r)
            out[(size_t)(m0 + quad * 4 + r) * DF + c * 16 + n] = acc[c][r];
}

extern "C" void kernel_launch(void* const* d_in, const int* in_sizes, int n_in,
                              void* d_out, int out_size, void* d_ws, size_t ws_size,
                              hipStream_t stream) {
    const float* feat    = (const float*)d_in[0];
    const float* weight  = (const float*)d_in[1];
    const int*   src     = (const int*)d_in[2];
    const int*   dst     = (const int*)d_in[3];
    const float* W_pool  = (const float*)d_in[4];
    const float* b_pool  = (const float*)d_in[5];
    const float* W_neigh = (const float*)d_in[6];
    const float* b_neigh = (const float*)d_in[7];
    float* out = (float*)d_out;

    char* ws = (char*)d_ws;
    unsigned short* featb  = (unsigned short*)(ws);              // 12,800,000 B
    unsigned short* hb     = (unsigned short*)(ws + 12800000);   // 12,800,256 B (50001 rows)
    unsigned short* Wp_f   = (unsigned short*)(ws + 25600512);   // 32,768 B
    unsigned short* Wn1_f  = (unsigned short*)(ws + 25633280);   // 32,768 B
    unsigned short* Wn2_f  = (unsigned short*)(ws + 25666048);   // 32,768 B
    int*   offsets   = (int*)  (ws + 25698816);                  // 200,000 B
    int*   nend      = (int*)  (ws + 25898816);                  // 200,000 B
    int*   bucketcnt = (int*)  (ws + 26098816);                  // 1,024 B
    uint2* staging   = (uint2*)(ws + 26099840);                  // 9,633,792 B
    uint2* edges     = (uint2*)(ws + 35733632);                  // 12,845,056 B (196*8192*8)
    unsigned short* neighb = (unsigned short*)(ws + 48578688);   // 12,800,000 B -> ~61.4 MB

    hipMemsetAsync(bucketcnt, 0, 1024, stream);

    // K1: PassA || featb conversion || W fragments || dummy hb row
    const int K1_BLOCKS = PA_BLOCKS + NF4 / 256 + NWG / 256 + 1;   // 250+6250+24+1
    k1_setup_bucket<<<K1_BLOCKS, 256, 0, stream>>>(
        feat, W_pool, W_neigh, src, dst, weight,
        featb, hb, Wp_f, Wn1_f, Wn2_f, bucketcnt, staging);

    // K2: gemm_pool (hb) || PassB (padded per-bucket edges + offsets/nend)
    k2_gemm_passb<<<GEMMB + NBUCK, 1024, 0, stream>>>(
        featb, Wp_f, b_pool, hb, bucketcnt, staging, offsets, nend, edges);

    // K3: neighb = bf16(segment_max(hb[src]*w, dst)), 0 for empty
    neigh_max_kernel<<<(N_NODES + 3) / 4, 256, 0, stream>>>(
        hb, offsets, nend, edges, neighb);

    // K4: out = featb @ Wn1^T + neighb @ Wn2^T + b_neigh
    gemm_out<<<782, 256, 0, stream>>>(
        featb, neighb, Wn1_f, Wn2_f, b_neigh, out);
}